// Round 14
// baseline (2421.382 us; speedup 1.0000x reference)
//
#include <hip/hip_runtime.h>

// RecurrentDecoder: prep -> ONE fused persistent kernel (L3 protocol, R10 base):
//   blocks 0..63   = GRU scan; h published once into append-only hist
//                    (write-through), consumers read CACHED (first-touch-
//                    after-write). ALL 64 scan flags packed in ONE 64B line
//                    (u8), poll = one line request per wave per iteration.
//                    x-prefetch pinned at step start (vmcnt(3)).
//   blocks 64..511 = dense-GEMM workers (LDS dbuf global_load_lds pipeline,
//                    XOR-swizzled, nt stores), gated by packed u8 frontier.

typedef __attribute__((ext_vector_type(8))) short s16x8;  // 8 bf16 (4 VGPRs)
typedef __attribute__((ext_vector_type(4))) float f32x4;
typedef __attribute__((ext_vector_type(4))) int   i32x4;

#define B_      16
#define TSTEPS  255
#define H_      1024
#define G_      3072
#define E_      512
#define V_      32000
#define NBLK_SCAN 64
#define NWORK     448
#define NBLK_TOT  512
#define NTILE_RB  32    // 4096/128
#define NTILE_CB  250   // 32000/128

__device__ __forceinline__ short f2bf(float f) {   // RNE f32 -> bf16 bits
  unsigned u = __float_as_uint(f);
  u = (u + 0x7fffu + ((u >> 16) & 1u)) >> 16;
  return (short)u;
}

__device__ __forceinline__ float frcp(float x) {
  float r;
  asm("v_rcp_f32 %0, %1" : "=v"(r) : "v"(x));
  return r;
}

// normal cached 16B load (L1/L2 path) — for append-only hist reads
#define GLD_C(dst, p)                                                          \
  asm volatile("global_load_dwordx4 %0, %1, off"                               \
               : "=v"(dst) : "v"(p) : "memory")
// cached f32 load, order-pinned (x prefetch)
#define LDF32(v, p)                                                            \
  asm volatile("global_load_dword %0, %1, off" : "=v"(v) : "v"(p))
// u8 flag primitives at the L3 coherence point
#define ST8_WT(p, x)                                                           \
  asm volatile("global_store_byte %0, %1, off sc0 sc1" :: "v"(p), "v"(x) : "memory")
#define LD8_SC(v, p)                                                           \
  asm volatile("global_load_ubyte %0, %1, off sc0 sc1\n\ts_waitcnt vmcnt(0)"   \
               : "=v"(v) : "v"(p) : "memory")

// async global->LDS 16B: HW writes lane l at (wave-uniform) ldsbase + l*16
__device__ __forceinline__ void gload_lds16(const short* g, void* l) {
  __builtin_amdgcn_global_load_lds((const __attribute__((address_space(1))) void*)g,
                                   (__attribute__((address_space(3))) void*)l,
                                   16, 0, 0);
}

// ---------- prep kernels ----------

// src f32 [K][N] -> dst bf16 [N][K]
__global__ void transpose_cvt(const float* __restrict__ src, short* __restrict__ dst,
                              int K, int N) {
  __shared__ float tile[32][33];
  const int n0 = blockIdx.x * 32, k0 = blockIdx.y * 32;
  const int tx = threadIdx.x, ty0 = threadIdx.y;  // (32,8)
#pragma unroll
  for (int yy = 0; yy < 4; ++yy) {
    int ty = ty0 + yy * 8;
    tile[ty][tx] = src[(size_t)(k0 + ty) * N + (n0 + tx)];
  }
  __syncthreads();
#pragma unroll
  for (int yy = 0; yy < 4; ++yy) {
    int ty = ty0 + yy * 8;
    dst[(size_t)(n0 + ty) * K + (k0 + tx)] = f2bf(tile[tx][ty]);
  }
}

// true_outputs (16,256,512) f32 -> teacher A bf16 [4096][512], row = t*16+b
__global__ void pack_teacher(const float* __restrict__ src, short* __restrict__ dst) {
  int idx = blockIdx.x * 256 + threadIdx.x;  // 262144 total
  int row = idx >> 6;
  int c8 = (idx & 63) << 3;
  int t = row >> 4, b = row & 15;
  s16x8 v = {};
  if (t < TSTEPS) {
    const float* s = src + ((size_t)(b * 256 + t)) * E_ + c8;
#pragma unroll
    for (int j = 0; j < 8; ++j) v[j] = f2bf(s[j]);
  }
  *(s16x8*)(dst + (size_t)row * E_ + c8) = v;
}

// hist rows 0..15 = bf16(latent) = h(0)
__global__ void init_h(const float* __restrict__ latent, short* __restrict__ hist) {
  int i = blockIdx.x * 256 + threadIdx.x;  // 16384
  hist[i] = f2bf(latent[i]);
}

// ---------- plain GEMM (xproj only; dispatch-boundary coherence) ----------
__global__ __launch_bounds__(256) void gemm_bf16(
    const short* __restrict__ A, const short* __restrict__ BT,
    const float* __restrict__ bias, float* __restrict__ C, int N, int K) {
  const int tid = threadIdx.x;
  const int lane = tid & 63, w = tid >> 6;
  const int r = lane & 15, q = lane >> 4;
  const int bm = blockIdx.y * 128, bn = blockIdx.x * 128;
  const int wm = bm + (w >> 1) * 64, wn = bn + (w & 1) * 64;
  const short* Ab = A + (size_t)(wm + r) * K + q * 8;
  const short* Bb = BT + (size_t)(wn + r) * K + q * 8;
  f32x4 acc[4][4] = {};
  s16x8 a0[4], b0[4], a1[4], b1[4];
  const int nk = K >> 5;
#define GL(AA, BB, kk)                                                         \
  {                                                                            \
    _Pragma("unroll") for (int i = 0; i < 4; ++i) {                            \
      AA[i] = *(const s16x8*)(Ab + (size_t)i * 16 * K + (kk) * 32);            \
    }                                                                          \
    _Pragma("unroll") for (int j = 0; j < 4; ++j) {                            \
      BB[j] = *(const s16x8*)(Bb + (size_t)j * 16 * K + (kk) * 32);            \
    }                                                                          \
  }
#define MM(AA, BB)                                                             \
  {                                                                            \
    _Pragma("unroll") for (int i = 0; i < 4; ++i)                              \
        _Pragma("unroll") for (int j = 0; j < 4; ++j)                          \
            acc[i][j] = __builtin_amdgcn_mfma_f32_16x16x32_bf16(               \
                AA[i], BB[j], acc[i][j], 0, 0, 0);                             \
  }
  GL(a0, b0, 0)
#pragma unroll 1
  for (int ks = 0; ks < nk; ks += 2) {
    GL(a1, b1, ks + 1)
    MM(a0, b0)
    if (ks + 2 < nk) GL(a0, b0, ks + 2)
    MM(a1, b1)
  }
#undef GL
#undef MM
#pragma unroll
  for (int j = 0; j < 4; ++j) {
    const int col = wn + j * 16 + r;
    const float bv = bias[col];
#pragma unroll
    for (int i = 0; i < 4; ++i) {
#pragma unroll
      for (int rr = 0; rr < 4; ++rr) {
        const int row = wm + i * 16 + q * 4 + rr;
        C[(size_t)row * N + col] = acc[i][j][rr] + bv;
      }
    }
  }
}

// ---------- fused persistent scan + dense GEMM ----------
// sync bytes: [0..63] scan flags u8 (one line); [64..127] frontier u8.
__global__ __launch_bounds__(256, 2) void fused_scan_gemm(
    const short* __restrict__ WrecT,   // [3072][1024] bf16
    const float* __restrict__ xproj,   // [4096][3072] f32 rows t*16+m
    const float* __restrict__ bias1,   // recurrent bias [3072]
    const float* __restrict__ latent,  // [16][1024] f32
    short* __restrict__ hist,          // [4112][1024] bf16; rows 16t.. = h(t)
    const short* __restrict__ DwT,     // [32000][1024] bf16
    const float* __restrict__ db,      // [32000]
    float* __restrict__ out,           // [16*255][32000]
    unsigned char* __restrict__ sync) {
  const int tid = threadIdx.x, lane = tid & 63, w = tid >> 6;
  const int r = lane & 15, q = lane >> 4;
  __shared__ s16x8 smem_v[2048];       // 32 KiB, shared between roles
  unsigned char* scanB  = sync;        // 64 bytes, ONE line
  unsigned char* frontB = sync + 64;   // 64 bytes, ONE line

  if (blockIdx.x < NBLK_SCAN) {
    // ================= scan role =================
    __builtin_amdgcn_s_setprio(3);
    float (*red)[3][64][4] = (float(*)[3][64][4])smem_v;   // 12 KiB
    const int c = blockIdx.x;
    s16x8 wb[3][8];
#pragma unroll
    for (int g = 0; g < 3; ++g)
#pragma unroll
      for (int s = 0; s < 8; ++s)
        wb[g][s] = *(const s16x8*)(WrecT + (size_t)(g * 1024 + c * 16 + r) * 1024 +
                                   (w * 8 + s) * 32 + q * 8);

    const int m = tid >> 4, nl = tid & 15, col = c * 16 + nl;
    float h = latent[m * 1024 + col];
    const float bz = bias1[col], brr = bias1[1024 + col], bhh = bias1[2048 + col];
    const float* xb = xproj + (size_t)m * G_;   // row t*16+m => base + t*16*G_
    float xz = xb[col], xr = xb[1024 + col], xh = xb[2048 + col];

    for (int t = 0; t < TSTEPS; ++t) {
      // h(t) fragment: NORMAL cached loads from append-only hist rows 16t..
      const short* hrow = hist + ((size_t)t * 16 + r) * 1024 + w * 256 + q * 8;
      i32x4 afi[8];
#pragma unroll
      for (int s = 0; s < 8; ++s) GLD_C(afi[s], hrow + s * 32);
      // x prefetch for t+1, pinned AFTER fragments (in-order vmcnt):
      float nz, nr, nh;
      {
        const float* xn = xb + (size_t)(t + 1) * 16 * G_;
        LDF32(nz, xn + col); LDF32(nr, xn + 1024 + col); LDF32(nh, xn + 2048 + col);
      }
      // wait fragments only (3 prefetch loads may remain outstanding)
      asm volatile("s_waitcnt vmcnt(3)"
                   : "+v"(afi[0]), "+v"(afi[1]), "+v"(afi[2]), "+v"(afi[3]),
                     "+v"(afi[4]), "+v"(afi[5]), "+v"(afi[6]), "+v"(afi[7])
                   :: "memory");
      __builtin_amdgcn_sched_barrier(0);
      f32x4 acc[3] = {};
#pragma unroll
      for (int s = 0; s < 8; ++s) {
        const s16x8 af = *(const s16x8*)&afi[s];
        acc[0] = __builtin_amdgcn_mfma_f32_16x16x32_bf16(af, wb[0][s], acc[0], 0, 0, 0);
        acc[1] = __builtin_amdgcn_mfma_f32_16x16x32_bf16(af, wb[1][s], acc[1], 0, 0, 0);
        acc[2] = __builtin_amdgcn_mfma_f32_16x16x32_bf16(af, wb[2][s], acc[2], 0, 0, 0);
      }
      *(f32x4*)&red[w][0][lane][0] = acc[0];
      *(f32x4*)&red[w][1][lane][0] = acc[1];
      *(f32x4*)&red[w][2][lane][0] = acc[2];
      __syncthreads();  // barrier#1: partials ready
      const int rl = (m >> 2) * 16 + nl, ri = m & 3;
      float rz = bz, rr2 = brr, rh = bhh;
#pragma unroll
      for (int ww = 0; ww < 4; ++ww) {
        rz += red[ww][0][rl][ri];
        rr2 += red[ww][1][rl][ri];
        rh += red[ww][2][rl][ri];
      }
      const float z = frcp(1.f + __expf(-(xz + rz)));
      const float rg = frcp(1.f + __expf(-(xr + rr2)));
      // tanh(x) = 1 - 2/(e^{2x}+1)
      const float e2 = __expf(2.f * (xh + rg * rh));
      const float hh = 1.f - 2.f * frcp(e2 + 1.f);
      h = z * h + (1.f - z) * hh;   // h stays f32 locally
      // publish h(t+1): ONE write-through store into hist rows 16(t+1)..
      const unsigned hb16 = (unsigned short)f2bf(h);
      const unsigned nb = __shfl(hb16, lane | 1, 64);
      const unsigned pv = hb16 | (nb << 16);
      if (!(tid & 1))
        __hip_atomic_store(
            (unsigned*)hist + (((size_t)(t + 1) * 16 + m) * 1024 + col) / 2,
            pv, __ATOMIC_RELAXED, __HIP_MEMORY_SCOPE_AGENT);
      __syncthreads();  // barrier#2: drains h stores + x prefetch together
      // commit prefetched x (vmcnt already 0 here -> free; rule-18 fence)
      asm volatile("s_waitcnt vmcnt(0)"
                   : "+v"(nz), "+v"(nr), "+v"(nh) :: "memory");
      __builtin_amdgcn_sched_barrier(0);
      xz = nz; xr = nr; xh = nh;
      if (tid == 0) {
        ST8_WT(scanB + c, (unsigned)(t + 1));
        if ((t & 7) == 7) ST8_WT(frontB + c, (unsigned)((t + 1) >> 3));
        if (t == TSTEPS - 1) ST8_WT(frontB + c, 32u);
      }
      if (t < TSTEPS - 1) {  // poll: ONE 64B line per wave per iteration
        unsigned v;
        LD8_SC(v, scanB + lane);
        while (!__all(v > (unsigned)t)) LD8_SC(v, scanB + lane);
      }
    }
  } else {
    // ================= dense GEMM worker role =================
    char* sb = (char*)smem_v;
    const int wr = w >> 1, wc = w & 1;
    const int xterm = ((q ^ ((r >> 1) & 3)) << 4);              // LDS slot swz
    const int swz8 = (((lane & 3) ^ ((lane >> 3) & 3)) << 3);   // src col swz
    const int j = blockIdx.x - NBLK_SCAN;  // 0..447
#pragma unroll 1
    for (int tq = j; tq < NTILE_RB * NTILE_CB; tq += NWORK) {
      const int rb = tq / NTILE_CB, cb = tq - rb * NTILE_CB;
      const unsigned need = (unsigned)(rb < 31 ? rb + 1 : 32);
      unsigned v;
      LD8_SC(v, frontB + lane);
      while (!__all(v >= need)) {
        __builtin_amdgcn_s_sleep(32);
        LD8_SC(v, frontB + lane);
      }
      // A from hist rows 16.. (append-only, first-touch-after-write coherent)
      const short* Ag = hist + (size_t)16 * 1024 + (size_t)rb * 128 * 1024;
      const short* Bg = DwT + (size_t)cb * 128 * 1024;
      f32x4 acc[4][4] = {};
#define STAGE(buf, kk)                                                         \
  {                                                                            \
    _Pragma("unroll") for (int it = 0; it < 2; ++it) {                         \
      const size_t go = (size_t)(w * 32 + it * 16 + (lane >> 2)) * 1024 +      \
                        (kk) * 32 + swz8;                                      \
      char* lb2 = sb + (buf) * 16384 + w * 2048 + it * 1024;                   \
      gload_lds16(Ag + go, lb2);                                               \
      gload_lds16(Bg + go, lb2 + 8192);                                        \
    }                                                                          \
  }
      STAGE(0, 0)
#pragma unroll 1
      for (int kk = 0; kk < 32; ++kk) {
        __syncthreads();             // staged kk visible; prev buf reads done
        if (kk < 31) STAGE((kk + 1) & 1, kk + 1)
        const char* ab = sb + (kk & 1) * 16384;
        s16x8 af[4], bf[4];
#pragma unroll
        for (int i = 0; i < 4; ++i)
          af[i] = *(const s16x8*)(ab + (wr * 64 + i * 16 + r) * 64 + xterm);
#pragma unroll
        for (int j5 = 0; j5 < 4; ++j5)
          bf[j5] = *(const s16x8*)(ab + 8192 + (wc * 64 + j5 * 16 + r) * 64 + xterm);
#pragma unroll
        for (int i = 0; i < 4; ++i)
#pragma unroll
          for (int j5 = 0; j5 < 4; ++j5)
            acc[i][j5] = __builtin_amdgcn_mfma_f32_16x16x32_bf16(
                af[i], bf[j5], acc[i][j5], 0, 0, 0);
      }
#undef STAGE
      const int wm = rb * 128 + wr * 64, wn = cb * 128 + wc * 64;
#pragma unroll
      for (int j2 = 0; j2 < 4; ++j2) {
        const int col = wn + j2 * 16 + r;
        const float bv = db[col];
#pragma unroll
        for (int i = 0; i < 4; ++i) {
#pragma unroll
          for (int rr = 0; rr < 4; ++rr) {
            const int arow = wm + i * 16 + q * 4 + rr;
            const int t = arow >> 4, mm = arow & 15;
            if (t < TSTEPS)
              __builtin_nontemporal_store(
                  acc[i][j2][rr] + bv,
                  &out[(size_t)(mm * TSTEPS + t) * V_ + col]);
          }
        }
      }
      __syncthreads();  // LDS WAR: next tile's STAGE(0,0) vs this tile's reads
    }
  }
}

// ---------- launch ----------
extern "C" void kernel_launch(void* const* d_in, const int* in_sizes, int n_in,
                              void* d_out, int out_size, void* d_ws, size_t ws_size,
                              hipStream_t stream) {
  const float* latent = (const float*)d_in[0];
  const float* trueo  = (const float*)d_in[1];
  const float* gk     = (const float*)d_in[2];
  const float* grk    = (const float*)d_in[3];
  const float* gbias  = (const float*)d_in[4];
  const float* dw     = (const float*)d_in[5];
  const float* db     = (const float*)d_in[6];
  float* out = (float*)d_out;
  char* ws = (char*)d_ws;
  short*    WrecT  = (short*)(ws + 0);          //  6,291,456  [3072][1024] bf16
  short*    GkT    = (short*)(ws + 6291456);    //  3,145,728  [3072][512]  bf16
  short*    DwT    = (short*)(ws + 9437184);    // 65,536,000  [32000][1024] bf16
  short*    teachA = (short*)(ws + 74973184);   //  4,194,304  [4096][512]  bf16 rows t*16+b
  float*    xproj  = (float*)(ws + 79167488);   // 50,331,648  [4096][3072] f32 rows t*16+m
  short*    hist   = (short*)(ws + 129499136);  //  8,421,376  [4112][1024] bf16 h-history
  unsigned char* syncb = (unsigned char*)(ws + 137920512); // 128 B flags (2 lines)

  hipMemsetAsync(syncb, 0, 256, stream);
  transpose_cvt<<<dim3(96, 32), dim3(32, 8), 0, stream>>>(grk, WrecT, 1024, 3072);
  transpose_cvt<<<dim3(96, 16), dim3(32, 8), 0, stream>>>(gk, GkT, 512, 3072);
  transpose_cvt<<<dim3(1000, 32), dim3(32, 8), 0, stream>>>(dw, DwT, 1024, 32000);
  pack_teacher<<<1024, 256, 0, stream>>>(trueo, teachA);
  gemm_bf16<<<dim3(24, 32), 256, 0, stream>>>(teachA, GkT, gbias, xproj, G_, E_);
  init_h<<<64, 256, 0, stream>>>(latent, hist);
  fused_scan_gemm<<<NBLK_TOT, 256, 0, stream>>>(WrecT, xproj, gbias + G_, latent,
                                                hist, DwT, db, out, (unsigned char*)syncb);
}

// Round 15
// 1041.622 us; speedup vs baseline: 2.3246x; 2.3246x over previous
//
#include <hip/hip_runtime.h>

// RecurrentDecoder: prep -> ONE fused persistent kernel (L3 protocol, R10 base):
//   blocks 0..63   = GRU scan; h published once into append-only hist
//                    (write-through), consumers read CACHED (first-touch-
//                    after-write). Per-WG u32 flags on SEPARATE 64B lines.
//                    x-prefetch issued at step start (vmcnt(3)) so the poll
//                    never waits on HBM.
//   blocks 64..511 = dense-GEMM workers (LDS dbuf global_load_lds pipeline,
//                    XOR-swizzled, nt stores), gated by frontier flags.

typedef __attribute__((ext_vector_type(8))) short s16x8;  // 8 bf16 (4 VGPRs)
typedef __attribute__((ext_vector_type(4))) float f32x4;
typedef __attribute__((ext_vector_type(4))) int   i32x4;

#define B_      16
#define TSTEPS  255
#define H_      1024
#define G_      3072
#define E_      512
#define V_      32000
#define NBLK_SCAN 64
#define NWORK     448
#define NBLK_TOT  512
#define NTILE_RB  32    // 4096/128
#define NTILE_CB  250   // 32000/128
#define FSTRIDE   16    // flags padded to 64B (separate lines per producer!)

__device__ __forceinline__ short f2bf(float f) {   // RNE f32 -> bf16 bits
  unsigned u = __float_as_uint(f);
  u = (u + 0x7fffu + ((u >> 16) & 1u)) >> 16;
  return (short)u;
}

__device__ __forceinline__ float frcp(float x) {
  float r;
  asm("v_rcp_f32 %0, %1" : "=v"(r) : "v"(x));
  return r;
}

// normal cached 16B load (L1/L2 path) — for append-only hist reads
#define GLD_C(dst, p)                                                          \
  asm volatile("global_load_dwordx4 %0, %1, off"                               \
               : "=v"(dst) : "v"(p) : "memory")
// cached f32 load, order-pinned (x prefetch)
#define LDF32(v, p)                                                            \
  asm volatile("global_load_dword %0, %1, off" : "=v"(v) : "v"(p))

// async global->LDS 16B: HW writes lane l at (wave-uniform) ldsbase + l*16
__device__ __forceinline__ void gload_lds16(const short* g, void* l) {
  __builtin_amdgcn_global_load_lds((const __attribute__((address_space(1))) void*)g,
                                   (__attribute__((address_space(3))) void*)l,
                                   16, 0, 0);
}

// ---------- prep kernels ----------

// src f32 [K][N] -> dst bf16 [N][K]
__global__ void transpose_cvt(const float* __restrict__ src, short* __restrict__ dst,
                              int K, int N) {
  __shared__ float tile[32][33];
  const int n0 = blockIdx.x * 32, k0 = blockIdx.y * 32;
  const int tx = threadIdx.x, ty0 = threadIdx.y;  // (32,8)
#pragma unroll
  for (int yy = 0; yy < 4; ++yy) {
    int ty = ty0 + yy * 8;
    tile[ty][tx] = src[(size_t)(k0 + ty) * N + (n0 + tx)];
  }
  __syncthreads();
#pragma unroll
  for (int yy = 0; yy < 4; ++yy) {
    int ty = ty0 + yy * 8;
    dst[(size_t)(n0 + ty) * K + (k0 + tx)] = f2bf(tile[tx][ty]);
  }
}

// true_outputs (16,256,512) f32 -> teacher A bf16 [4096][512], row = t*16+b
__global__ void pack_teacher(const float* __restrict__ src, short* __restrict__ dst) {
  int idx = blockIdx.x * 256 + threadIdx.x;  // 262144 total
  int row = idx >> 6;
  int c8 = (idx & 63) << 3;
  int t = row >> 4, b = row & 15;
  s16x8 v = {};
  if (t < TSTEPS) {
    const float* s = src + ((size_t)(b * 256 + t)) * E_ + c8;
#pragma unroll
    for (int j = 0; j < 8; ++j) v[j] = f2bf(s[j]);
  }
  *(s16x8*)(dst + (size_t)row * E_ + c8) = v;
}

// hist rows 0..15 = bf16(latent) = h(0)
__global__ void init_h(const float* __restrict__ latent, short* __restrict__ hist) {
  int i = blockIdx.x * 256 + threadIdx.x;  // 16384
  hist[i] = f2bf(latent[i]);
}

// ---------- plain GEMM (xproj only; dispatch-boundary coherence) ----------
__global__ __launch_bounds__(256) void gemm_bf16(
    const short* __restrict__ A, const short* __restrict__ BT,
    const float* __restrict__ bias, float* __restrict__ C, int N, int K) {
  const int tid = threadIdx.x;
  const int lane = tid & 63, w = tid >> 6;
  const int r = lane & 15, q = lane >> 4;
  const int bm = blockIdx.y * 128, bn = blockIdx.x * 128;
  const int wm = bm + (w >> 1) * 64, wn = bn + (w & 1) * 64;
  const short* Ab = A + (size_t)(wm + r) * K + q * 8;
  const short* Bb = BT + (size_t)(wn + r) * K + q * 8;
  f32x4 acc[4][4] = {};
  s16x8 a0[4], b0[4], a1[4], b1[4];
  const int nk = K >> 5;
#define GL(AA, BB, kk)                                                         \
  {                                                                            \
    _Pragma("unroll") for (int i = 0; i < 4; ++i) {                            \
      AA[i] = *(const s16x8*)(Ab + (size_t)i * 16 * K + (kk) * 32);            \
    }                                                                          \
    _Pragma("unroll") for (int j = 0; j < 4; ++j) {                            \
      BB[j] = *(const s16x8*)(Bb + (size_t)j * 16 * K + (kk) * 32);            \
    }                                                                          \
  }
#define MM(AA, BB)                                                             \
  {                                                                            \
    _Pragma("unroll") for (int i = 0; i < 4; ++i)                              \
        _Pragma("unroll") for (int j = 0; j < 4; ++j)                          \
            acc[i][j] = __builtin_amdgcn_mfma_f32_16x16x32_bf16(               \
                AA[i], BB[j], acc[i][j], 0, 0, 0);                             \
  }
  GL(a0, b0, 0)
#pragma unroll 1
  for (int ks = 0; ks < nk; ks += 2) {
    GL(a1, b1, ks + 1)
    MM(a0, b0)
    if (ks + 2 < nk) GL(a0, b0, ks + 2)
    MM(a1, b1)
  }
#undef GL
#undef MM
#pragma unroll
  for (int j = 0; j < 4; ++j) {
    const int col = wn + j * 16 + r;
    const float bv = bias[col];
#pragma unroll
    for (int i = 0; i < 4; ++i) {
#pragma unroll
      for (int rr = 0; rr < 4; ++rr) {
        const int row = wm + i * 16 + q * 4 + rr;
        C[(size_t)row * N + col] = acc[i][j][rr] + bv;
      }
    }
  }
}

// ---------- fused persistent scan + dense GEMM ----------
// sync: [0..1023] scan flags (u32, 64B apart); [1024..2047] frontier flags.
__global__ __launch_bounds__(256, 2) void fused_scan_gemm(
    const short* __restrict__ WrecT,   // [3072][1024] bf16
    const float* __restrict__ xproj,   // [4096][3072] f32 rows t*16+m
    const float* __restrict__ bias1,   // recurrent bias [3072]
    const float* __restrict__ latent,  // [16][1024] f32
    short* __restrict__ hist,          // [4112][1024] bf16; rows 16t.. = h(t)
    const short* __restrict__ DwT,     // [32000][1024] bf16
    const float* __restrict__ db,      // [32000]
    float* __restrict__ out,           // [16*255][32000]
    unsigned* __restrict__ sync) {
  const int tid = threadIdx.x, lane = tid & 63, w = tid >> 6;
  const int r = lane & 15, q = lane >> 4;
  __shared__ s16x8 smem_v[2048];       // 32 KiB, shared between roles
  unsigned* scanflag = sync;
  unsigned* frontier = sync + 1024;

  if (blockIdx.x < NBLK_SCAN) {
    // ================= scan role =================
    __builtin_amdgcn_s_setprio(3);
    float (*red)[3][64][4] = (float(*)[3][64][4])smem_v;   // 12 KiB
    const int c = blockIdx.x;
    s16x8 wb[3][8];
#pragma unroll
    for (int g = 0; g < 3; ++g)
#pragma unroll
      for (int s = 0; s < 8; ++s)
        wb[g][s] = *(const s16x8*)(WrecT + (size_t)(g * 1024 + c * 16 + r) * 1024 +
                                   (w * 8 + s) * 32 + q * 8);

    const int m = tid >> 4, nl = tid & 15, col = c * 16 + nl;
    float h = latent[m * 1024 + col];
    const float bz = bias1[col], brr = bias1[1024 + col], bhh = bias1[2048 + col];
    const float* xb = xproj + (size_t)m * G_;   // row t*16+m => base + t*16*G_
    float xz = xb[col], xr = xb[1024 + col], xh = xb[2048 + col];

    for (int t = 0; t < TSTEPS; ++t) {
      // h(t) fragment: NORMAL cached loads from append-only hist rows 16t..
      const short* hrow = hist + ((size_t)t * 16 + r) * 1024 + w * 256 + q * 8;
      i32x4 afi[8];
#pragma unroll
      for (int s = 0; s < 8; ++s) GLD_C(afi[s], hrow + s * 32);
      // x prefetch for t+1 issued NOW (drains under barrier#1, never in the
      // poll's vmcnt shadow). Pad rows exist: zero teacher.
      float nz, nr, nh;
      {
        const float* xn = xb + (size_t)(t + 1) * 16 * G_;
        LDF32(nz, xn + col); LDF32(nr, xn + 1024 + col); LDF32(nh, xn + 2048 + col);
      }
      // wait fragments only (3 prefetch loads may remain outstanding)
      asm volatile("s_waitcnt vmcnt(3)"
                   : "+v"(afi[0]), "+v"(afi[1]), "+v"(afi[2]), "+v"(afi[3]),
                     "+v"(afi[4]), "+v"(afi[5]), "+v"(afi[6]), "+v"(afi[7])
                   :: "memory");
      __builtin_amdgcn_sched_barrier(0);
      f32x4 acc[3] = {};
#pragma unroll
      for (int s = 0; s < 8; ++s) {
        const s16x8 af = *(const s16x8*)&afi[s];
        acc[0] = __builtin_amdgcn_mfma_f32_16x16x32_bf16(af, wb[0][s], acc[0], 0, 0, 0);
        acc[1] = __builtin_amdgcn_mfma_f32_16x16x32_bf16(af, wb[1][s], acc[1], 0, 0, 0);
        acc[2] = __builtin_amdgcn_mfma_f32_16x16x32_bf16(af, wb[2][s], acc[2], 0, 0, 0);
      }
      *(f32x4*)&red[w][0][lane][0] = acc[0];
      *(f32x4*)&red[w][1][lane][0] = acc[1];
      *(f32x4*)&red[w][2][lane][0] = acc[2];
      __syncthreads();  // barrier#1: partials ready (drains x prefetch too)
      const int rl = (m >> 2) * 16 + nl, ri = m & 3;
      float rz = bz, rr2 = brr, rh = bhh;
#pragma unroll
      for (int ww = 0; ww < 4; ++ww) {
        rz += red[ww][0][rl][ri];
        rr2 += red[ww][1][rl][ri];
        rh += red[ww][2][rl][ri];
      }
      const float z = frcp(1.f + __expf(-(xz + rz)));
      const float rg = frcp(1.f + __expf(-(xr + rr2)));
      // tanh(x) = 1 - 2/(e^{2x}+1): v_exp + v_rcp, no libm call
      const float e2 = __expf(2.f * (xh + rg * rh));
      const float hh = 1.f - 2.f * frcp(e2 + 1.f);
      h = z * h + (1.f - z) * hh;   // h stays f32 locally
      // publish h(t+1): ONE write-through store into hist rows 16(t+1)..
      const unsigned hb16 = (unsigned short)f2bf(h);
      const unsigned nb = __shfl(hb16, lane | 1, 64);
      const unsigned pv = hb16 | (nb << 16);
      if (!(tid & 1))
        __hip_atomic_store(
            (unsigned*)hist + (((size_t)(t + 1) * 16 + m) * 1024 + col) / 2,
            pv, __ATOMIC_RELAXED, __HIP_MEMORY_SCOPE_AGENT);
      __syncthreads();  // barrier#2: drains h stores -> visible at L3
      // commit prefetched x (vmcnt already 0 here -> free; rule-18 fence)
      asm volatile("s_waitcnt vmcnt(0)"
                   : "+v"(nz), "+v"(nr), "+v"(nh) :: "memory");
      __builtin_amdgcn_sched_barrier(0);
      xz = nz; xr = nr; xh = nh;
      if (tid == 0) {
        __hip_atomic_store(&scanflag[c * FSTRIDE], (unsigned)(t + 1),
                           __ATOMIC_RELAXED, __HIP_MEMORY_SCOPE_AGENT);
        if ((t & 7) == 7)
          __hip_atomic_store(&frontier[c * FSTRIDE], (unsigned)(t + 1),
                             __ATOMIC_RELAXED, __HIP_MEMORY_SCOPE_AGENT);
      }
      if (t < TSTEPS - 1) {  // poll all 64 scan flags (sc-bypass, clean queue)
        const unsigned* fp = &scanflag[lane * FSTRIDE];
        unsigned v = __hip_atomic_load(fp, __ATOMIC_RELAXED,
                                       __HIP_MEMORY_SCOPE_AGENT);
        while (!__all(v > (unsigned)t))
          v = __hip_atomic_load(fp, __ATOMIC_RELAXED, __HIP_MEMORY_SCOPE_AGENT);
      }
    }
    // epilogue: final h rows drained by last barrier#2 -> frontier 256
    if (tid == 0)
      __hip_atomic_store(&frontier[c * FSTRIDE], 256u,
                         __ATOMIC_RELAXED, __HIP_MEMORY_SCOPE_AGENT);
  } else {
    // ================= dense GEMM worker role =================
    char* sb = (char*)smem_v;
    const int wr = w >> 1, wc = w & 1;
    const int xterm = ((q ^ ((r >> 1) & 3)) << 4);              // LDS slot swz
    const int swz8 = (((lane & 3) ^ ((lane >> 3) & 3)) << 3);   // src col swz
    const int j = blockIdx.x - NBLK_SCAN;  // 0..447
#pragma unroll 1
    for (int tq = j; tq < NTILE_RB * NTILE_CB; tq += NWORK) {
      const int rb = tq / NTILE_CB, cb = tq - rb * NTILE_CB;
      const unsigned need = (unsigned)(rb < 31 ? 8 * rb + 8 : 256);
      unsigned v = __hip_atomic_load(&frontier[lane * FSTRIDE], __ATOMIC_RELAXED,
                                     __HIP_MEMORY_SCOPE_AGENT);
      while (!__all(v >= need)) {
        __builtin_amdgcn_s_sleep(32);
        v = __hip_atomic_load(&frontier[lane * FSTRIDE], __ATOMIC_RELAXED,
                              __HIP_MEMORY_SCOPE_AGENT);
      }
      // A from hist rows 16.. (append-only, first-touch-after-write coherent)
      const short* Ag = hist + (size_t)16 * 1024 + (size_t)rb * 128 * 1024;
      const short* Bg = DwT + (size_t)cb * 128 * 1024;
      f32x4 acc[4][4] = {};
#define STAGE(buf, kk)                                                         \
  {                                                                            \
    _Pragma("unroll") for (int it = 0; it < 2; ++it) {                         \
      const size_t go = (size_t)(w * 32 + it * 16 + (lane >> 2)) * 1024 +      \
                        (kk) * 32 + swz8;                                      \
      char* lb2 = sb + (buf) * 16384 + w * 2048 + it * 1024;                   \
      gload_lds16(Ag + go, lb2);                                               \
      gload_lds16(Bg + go, lb2 + 8192);                                        \
    }                                                                          \
  }
      STAGE(0, 0)
#pragma unroll 1
      for (int kk = 0; kk < 32; ++kk) {
        __syncthreads();             // staged kk visible; prev buf reads done
        if (kk < 31) STAGE((kk + 1) & 1, kk + 1)
        const char* ab = sb + (kk & 1) * 16384;
        s16x8 af[4], bf[4];
#pragma unroll
        for (int i = 0; i < 4; ++i)
          af[i] = *(const s16x8*)(ab + (wr * 64 + i * 16 + r) * 64 + xterm);
#pragma unroll
        for (int j5 = 0; j5 < 4; ++j5)
          bf[j5] = *(const s16x8*)(ab + 8192 + (wc * 64 + j5 * 16 + r) * 64 + xterm);
#pragma unroll
        for (int i = 0; i < 4; ++i)
#pragma unroll
          for (int j5 = 0; j5 < 4; ++j5)
            acc[i][j5] = __builtin_amdgcn_mfma_f32_16x16x32_bf16(
                af[i], bf[j5], acc[i][j5], 0, 0, 0);
      }
#undef STAGE
      const int wm = rb * 128 + wr * 64, wn = cb * 128 + wc * 64;
#pragma unroll
      for (int j2 = 0; j2 < 4; ++j2) {
        const int col = wn + j2 * 16 + r;
        const float bv = db[col];
#pragma unroll
        for (int i = 0; i < 4; ++i) {
#pragma unroll
          for (int rr = 0; rr < 4; ++rr) {
            const int arow = wm + i * 16 + q * 4 + rr;
            const int t = arow >> 4, mm = arow & 15;
            if (t < TSTEPS)
              __builtin_nontemporal_store(
                  acc[i][j2][rr] + bv,
                  &out[(size_t)(mm * TSTEPS + t) * V_ + col]);
          }
        }
      }
      __syncthreads();  // LDS WAR: next tile's STAGE(0,0) vs this tile's reads
    }
  }
}

// ---------- launch ----------
extern "C" void kernel_launch(void* const* d_in, const int* in_sizes, int n_in,
                              void* d_out, int out_size, void* d_ws, size_t ws_size,
                              hipStream_t stream) {
  const float* latent = (const float*)d_in[0];
  const float* trueo  = (const float*)d_in[1];
  const float* gk     = (const float*)d_in[2];
  const float* grk    = (const float*)d_in[3];
  const float* gbias  = (const float*)d_in[4];
  const float* dw     = (const float*)d_in[5];
  const float* db     = (const float*)d_in[6];
  float* out = (float*)d_out;
  char* ws = (char*)d_ws;
  short*    WrecT  = (short*)(ws + 0);          //  6,291,456  [3072][1024] bf16
  short*    GkT    = (short*)(ws + 6291456);    //  3,145,728  [3072][512]  bf16
  short*    DwT    = (short*)(ws + 9437184);    // 65,536,000  [32000][1024] bf16
  short*    teachA = (short*)(ws + 74973184);   //  4,194,304  [4096][512]  bf16 rows t*16+b
  float*    xproj  = (float*)(ws + 79167488);   // 50,331,648  [4096][3072] f32 rows t*16+m
  short*    hist   = (short*)(ws + 129499136);  //  8,421,376  [4112][1024] bf16 h-history
  unsigned* syncb  = (unsigned*)(ws + 137920512); //    8,192  scanflags + frontier

  hipMemsetAsync(syncb, 0, 8192, stream);
  transpose_cvt<<<dim3(96, 32), dim3(32, 8), 0, stream>>>(grk, WrecT, 1024, 3072);
  transpose_cvt<<<dim3(96, 16), dim3(32, 8), 0, stream>>>(gk, GkT, 512, 3072);
  transpose_cvt<<<dim3(1000, 32), dim3(32, 8), 0, stream>>>(dw, DwT, 1024, 32000);
  pack_teacher<<<1024, 256, 0, stream>>>(trueo, teachA);
  gemm_bf16<<<dim3(24, 32), 256, 0, stream>>>(teachA, GkT, gbias, xproj, G_, E_);
  init_h<<<64, 256, 0, stream>>>(latent, hist);
  fused_scan_gemm<<<NBLK_TOT, 256, 0, stream>>>(WrecT, xproj, gbias + G_, latent,
                                                hist, DwT, db, out, syncb);
}

// Round 16
// 929.790 us; speedup vs baseline: 2.6042x; 1.1203x over previous
//
#include <hip/hip_runtime.h>

// RecurrentDecoder: x_proj GEMM -> ONE fused persistent kernel:
//   blocks 0..63   = GRU scan. h exchanged through an APPEND-ONLY history
//                    buffer (hist row-block t = h(t)): producers write-through
//                    once; consumers use NORMAL CACHED loads (first touch
//                    after write => coherent; per-XCD L2 serves 8 WGs from one
//                    L3 fetch). R5 flag protocol (sc-bypass, 64B-padded).
//   blocks 64..511 = dense-GEMM workers (LDS dbuf global_load_lds pipeline,
//                    XOR-swizzled, nt stores), reading A from hist+16 rows,
//                    gated by frontier flags published every 8 steps.

typedef __attribute__((ext_vector_type(8))) short s16x8;  // 8 bf16 (4 VGPRs)
typedef __attribute__((ext_vector_type(4))) float f32x4;
typedef __attribute__((ext_vector_type(4))) int   i32x4;

#define B_      16
#define TSTEPS  255
#define H_      1024
#define G_      3072
#define E_      512
#define V_      32000
#define MROWS   4080   // B_*TSTEPS
#define MPAD    4096
#define NBLK_SCAN 64
#define NWORK     448
#define NBLK_TOT  512
#define NTILE_RB  32    // 4096/128
#define NTILE_CB  250   // 32000/128
#define FSTRIDE   16    // flags padded to 64B

__device__ __forceinline__ short f2bf(float f) {   // RNE f32 -> bf16 bits
  unsigned u = __float_as_uint(f);
  u = (u + 0x7fffu + ((u >> 16) & 1u)) >> 16;
  return (short)u;
}

__device__ __forceinline__ float frcp(float x) {
  float r;
  asm("v_rcp_f32 %0, %1" : "=v"(r) : "v"(x));
  return r;
}

// normal cached 16B load (L1/L2 path) — for append-only hist reads
#define GLD_C(dst, p)                                                          \
  asm volatile("global_load_dwordx4 %0, %1, off"                               \
               : "=v"(dst) : "v"(p) : "memory")

// async global->LDS 16B: HW writes lane l at (wave-uniform) ldsbase + l*16
__device__ __forceinline__ void gload_lds16(const short* g, void* l) {
  __builtin_amdgcn_global_load_lds((const __attribute__((address_space(1))) void*)g,
                                   (__attribute__((address_space(3))) void*)l,
                                   16, 0, 0);
}

// ---------- prep kernels ----------

// src f32 [K][N] -> dst bf16 [N][K]
__global__ void transpose_cvt(const float* __restrict__ src, short* __restrict__ dst,
                              int K, int N) {
  __shared__ float tile[32][33];
  const int n0 = blockIdx.x * 32, k0 = blockIdx.y * 32;
  const int tx = threadIdx.x, ty0 = threadIdx.y;  // (32,8)
#pragma unroll
  for (int yy = 0; yy < 4; ++yy) {
    int ty = ty0 + yy * 8;
    tile[ty][tx] = src[(size_t)(k0 + ty) * N + (n0 + tx)];
  }
  __syncthreads();
#pragma unroll
  for (int yy = 0; yy < 4; ++yy) {
    int ty = ty0 + yy * 8;
    dst[(size_t)(n0 + ty) * K + (k0 + tx)] = f2bf(tile[tx][ty]);
  }
}

// true_outputs (16,256,512) f32 -> teacher A bf16 [4096][512], row = t*16+b
__global__ void pack_teacher(const float* __restrict__ src, short* __restrict__ dst) {
  int idx = blockIdx.x * 256 + threadIdx.x;  // 262144 total
  int row = idx >> 6;
  int c8 = (idx & 63) << 3;
  int t = row >> 4, b = row & 15;
  s16x8 v = {};
  if (t < TSTEPS) {
    const float* s = src + ((size_t)(b * 256 + t)) * E_ + c8;
#pragma unroll
    for (int j = 0; j < 8; ++j) v[j] = f2bf(s[j]);
  }
  *(s16x8*)(dst + (size_t)row * E_ + c8) = v;
}

// hist rows 0..15 = bf16(latent) = h(0)
__global__ void init_h(const float* __restrict__ latent, short* __restrict__ hist) {
  int i = blockIdx.x * 256 + threadIdx.x;  // 16384
  hist[i] = f2bf(latent[i]);
}

// ---------- plain GEMM (xproj only; dispatch-boundary coherence) ----------
__global__ __launch_bounds__(256) void gemm_bf16(
    const short* __restrict__ A, const short* __restrict__ BT,
    const float* __restrict__ bias, float* __restrict__ C, int N, int K) {
  const int tid = threadIdx.x;
  const int lane = tid & 63, w = tid >> 6;
  const int r = lane & 15, q = lane >> 4;
  const int bm = blockIdx.y * 128, bn = blockIdx.x * 128;
  const int wm = bm + (w >> 1) * 64, wn = bn + (w & 1) * 64;
  const short* Ab = A + (size_t)(wm + r) * K + q * 8;
  const short* Bb = BT + (size_t)(wn + r) * K + q * 8;
  f32x4 acc[4][4] = {};
  s16x8 a0[4], b0[4], a1[4], b1[4];
  const int nk = K >> 5;
#define GL(AA, BB, kk)                                                         \
  {                                                                            \
    _Pragma("unroll") for (int i = 0; i < 4; ++i) {                            \
      AA[i] = *(const s16x8*)(Ab + (size_t)i * 16 * K + (kk) * 32);            \
    }                                                                          \
    _Pragma("unroll") for (int j = 0; j < 4; ++j) {                            \
      BB[j] = *(const s16x8*)(Bb + (size_t)j * 16 * K + (kk) * 32);            \
    }                                                                          \
  }
#define MM(AA, BB)                                                             \
  {                                                                            \
    _Pragma("unroll") for (int i = 0; i < 4; ++i)                              \
        _Pragma("unroll") for (int j = 0; j < 4; ++j)                          \
            acc[i][j] = __builtin_amdgcn_mfma_f32_16x16x32_bf16(               \
                AA[i], BB[j], acc[i][j], 0, 0, 0);                             \
  }
  GL(a0, b0, 0)
#pragma unroll 1
  for (int ks = 0; ks < nk; ks += 2) {
    GL(a1, b1, ks + 1)
    MM(a0, b0)
    if (ks + 2 < nk) GL(a0, b0, ks + 2)
    MM(a1, b1)
  }
#undef GL
#undef MM
#pragma unroll
  for (int j = 0; j < 4; ++j) {
    const int col = wn + j * 16 + r;
    const float bv = bias[col];
#pragma unroll
    for (int i = 0; i < 4; ++i) {
#pragma unroll
      for (int rr = 0; rr < 4; ++rr) {
        const int row = wm + i * 16 + q * 4 + rr;
        C[(size_t)row * N + col] = acc[i][j][rr] + bv;
      }
    }
  }
}

// ---------- fused persistent scan + dense GEMM ----------
// sync: [0..1023] scan flags (sc-bypass, 64B apart); [1024..2047] frontier.
__global__ __launch_bounds__(256, 2) void fused_scan_gemm(
    const short* __restrict__ WrecT,   // [3072][1024] bf16
    const float* __restrict__ xproj,   // [4096][3072] f32 rows t*16+m
    const float* __restrict__ bias1,   // recurrent bias [3072]
    const float* __restrict__ latent,  // [16][1024] f32
    short* __restrict__ hist,          // [4112][1024] bf16; rows 16t.. = h(t)
    const short* __restrict__ DwT,     // [32000][1024] bf16
    const float* __restrict__ db,      // [32000]
    float* __restrict__ out,           // [16*255][32000]
    unsigned* __restrict__ sync) {
  const int tid = threadIdx.x, lane = tid & 63, w = tid >> 6;
  const int r = lane & 15, q = lane >> 4;
  __shared__ s16x8 smem_v[2048];       // 32 KiB, shared between roles
  unsigned* scanflag = sync;
  unsigned* frontier = sync + 1024;

  if (blockIdx.x < NBLK_SCAN) {
    // ================= scan role =================
    __builtin_amdgcn_s_setprio(3);
    float (*red)[3][64][4] = (float(*)[3][64][4])smem_v;   // 12 KiB
    const int c = blockIdx.x;
    s16x8 wb[3][8];
#pragma unroll
    for (int g = 0; g < 3; ++g)
#pragma unroll
      for (int s = 0; s < 8; ++s)
        wb[g][s] = *(const s16x8*)(WrecT + (size_t)(g * 1024 + c * 16 + r) * 1024 +
                                   (w * 8 + s) * 32 + q * 8);

    const int m = tid >> 4, nl = tid & 15, col = c * 16 + nl;
    float h = latent[m * 1024 + col];
    const float bz = bias1[col], brr = bias1[1024 + col], bhh = bias1[2048 + col];
    const float* xb = xproj + (size_t)m * G_;   // row t*16+m => base + t*16*G_
    float xz = xb[col], xr = xb[1024 + col], xh = xb[2048 + col];

    for (int t = 0; t < TSTEPS; ++t) {
      // h(t) fragment: NORMAL cached loads from append-only hist rows 16t..
      const short* hrow = hist + ((size_t)t * 16 + r) * 1024 + w * 256 + q * 8;
      i32x4 afi[8];
#pragma unroll
      for (int s = 0; s < 8; ++s) GLD_C(afi[s], hrow + s * 32);
      asm volatile("s_waitcnt vmcnt(0)"
                   : "+v"(afi[0]), "+v"(afi[1]), "+v"(afi[2]), "+v"(afi[3]),
                     "+v"(afi[4]), "+v"(afi[5]), "+v"(afi[6]), "+v"(afi[7])
                   :: "memory");
      __builtin_amdgcn_sched_barrier(0);
      f32x4 acc[3] = {};
#pragma unroll
      for (int s = 0; s < 8; ++s) {
        const s16x8 af = *(const s16x8*)&afi[s];
        acc[0] = __builtin_amdgcn_mfma_f32_16x16x32_bf16(af, wb[0][s], acc[0], 0, 0, 0);
        acc[1] = __builtin_amdgcn_mfma_f32_16x16x32_bf16(af, wb[1][s], acc[1], 0, 0, 0);
        acc[2] = __builtin_amdgcn_mfma_f32_16x16x32_bf16(af, wb[2][s], acc[2], 0, 0, 0);
      }
      *(f32x4*)&red[w][0][lane][0] = acc[0];
      *(f32x4*)&red[w][1][lane][0] = acc[1];
      *(f32x4*)&red[w][2][lane][0] = acc[2];
      __syncthreads();  // partials ready (also drains prev prefetch)
      const int rl = (m >> 2) * 16 + nl, ri = m & 3;
      float rz = bz, rr2 = brr, rh = bhh;
#pragma unroll
      for (int ww = 0; ww < 4; ++ww) {
        rz += red[ww][0][rl][ri];
        rr2 += red[ww][1][rl][ri];
        rh += red[ww][2][rl][ri];
      }
      const float z = frcp(1.f + __expf(-(xz + rz)));
      const float rg = frcp(1.f + __expf(-(xr + rr2)));
      const float hh = tanhf(xh + rg * rh);
      h = z * h + (1.f - z) * hh;   // h stays f32 locally
      // publish h(t+1): ONE write-through store into hist rows 16(t+1)..
      const unsigned hb16 = (unsigned short)f2bf(h);
      const unsigned nb = __shfl(hb16, lane | 1, 64);
      const unsigned pv = hb16 | (nb << 16);
      if (!(tid & 1))
        __hip_atomic_store(
            (unsigned*)hist + (((size_t)(t + 1) * 16 + m) * 1024 + col) / 2,
            pv, __ATOMIC_RELAXED, __HIP_MEMORY_SCOPE_AGENT);
      __syncthreads();  // drains the h stores -> visible at L3
      if (tid == 0)
        __hip_atomic_store(&scanflag[c * FSTRIDE], (unsigned)(t + 1),
                           __ATOMIC_RELAXED, __HIP_MEMORY_SCOPE_AGENT);
      if ((t & 7) == 7) {  // worker-frontier flag, 1-in-8 steps
        if (tid == 0)
          __hip_atomic_store(&frontier[c * FSTRIDE], (unsigned)(t + 1),
                             __ATOMIC_RELAXED, __HIP_MEMORY_SCOPE_AGENT);
      }
      {  // prefetch next step's x slice (pad rows exist: zero teacher)
        const float* xn = xb + (size_t)(t + 1) * 16 * G_;
        xz = xn[col]; xr = xn[1024 + col]; xh = xn[2048 + col];
      }
      if (t < TSTEPS - 1) {  // poll all 64 scan flags (sc-bypass, self-paced)
        const unsigned* fp = &scanflag[lane * FSTRIDE];
        unsigned v = __hip_atomic_load(fp, __ATOMIC_RELAXED,
                                       __HIP_MEMORY_SCOPE_AGENT);
        while (!__all(v > (unsigned)t))
          v = __hip_atomic_load(fp, __ATOMIC_RELAXED, __HIP_MEMORY_SCOPE_AGENT);
      }
    }
    // epilogue: final h rows already drained (barrier above) -> frontier 256
    if (tid == 0)
      __hip_atomic_store(&frontier[c * FSTRIDE], 256u,
                         __ATOMIC_RELAXED, __HIP_MEMORY_SCOPE_AGENT);
  } else {
    // ================= dense GEMM worker role =================
    char* sb = (char*)smem_v;
    const int wr = w >> 1, wc = w & 1;
    const int xterm = ((q ^ ((r >> 1) & 3)) << 4);              // LDS slot swz
    const int swz8 = (((lane & 3) ^ ((lane >> 3) & 3)) << 3);   // src col swz
    const int j = blockIdx.x - NBLK_SCAN;  // 0..447
#pragma unroll 1
    for (int tq = j; tq < NTILE_RB * NTILE_CB; tq += NWORK) {
      const int rb = tq / NTILE_CB, cb = tq - rb * NTILE_CB;
      const unsigned need = (unsigned)(rb < 31 ? 8 * rb + 8 : 256);
      unsigned v = __hip_atomic_load(&frontier[lane * FSTRIDE], __ATOMIC_RELAXED,
                                     __HIP_MEMORY_SCOPE_AGENT);
      while (!__all(v >= need)) {
        __builtin_amdgcn_s_sleep(32);
        v = __hip_atomic_load(&frontier[lane * FSTRIDE], __ATOMIC_RELAXED,
                              __HIP_MEMORY_SCOPE_AGENT);
      }
      // A from hist rows 16.. (= old gruout rows); normal loads, coherent
      const short* Ag = hist + (size_t)16 * 1024 + (size_t)rb * 128 * 1024;
      const short* Bg = DwT + (size_t)cb * 128 * 1024;
      f32x4 acc[4][4] = {};
#define STAGE(buf, kk)                                                         \
  {                                                                            \
    _Pragma("unroll") for (int it = 0; it < 2; ++it) {                         \
      const size_t go = (size_t)(w * 32 + it * 16 + (lane >> 2)) * 1024 +      \
                        (kk) * 32 + swz8;                                      \
      char* lb2 = sb + (buf) * 16384 + w * 2048 + it * 1024;                   \
      gload_lds16(Ag + go, lb2);                                               \
      gload_lds16(Bg + go, lb2 + 8192);                                        \
    }                                                                          \
  }
      STAGE(0, 0)
#pragma unroll 1
      for (int kk = 0; kk < 32; ++kk) {
        __syncthreads();             // staged kk visible; prev buf reads done
        if (kk < 31) STAGE((kk + 1) & 1, kk + 1)
        const char* ab = sb + (kk & 1) * 16384;
        s16x8 af[4], bf[4];
#pragma unroll
        for (int i = 0; i < 4; ++i)
          af[i] = *(const s16x8*)(ab + (wr * 64 + i * 16 + r) * 64 + xterm);
#pragma unroll
        for (int j5 = 0; j5 < 4; ++j5)
          bf[j5] = *(const s16x8*)(ab + 8192 + (wc * 64 + j5 * 16 + r) * 64 + xterm);
#pragma unroll
        for (int i = 0; i < 4; ++i)
#pragma unroll
          for (int j5 = 0; j5 < 4; ++j5)
            acc[i][j5] = __builtin_amdgcn_mfma_f32_16x16x32_bf16(
                af[i], bf[j5], acc[i][j5], 0, 0, 0);
      }
#undef STAGE
      const int wm = rb * 128 + wr * 64, wn = cb * 128 + wc * 64;
#pragma unroll
      for (int j2 = 0; j2 < 4; ++j2) {
        const int col = wn + j2 * 16 + r;
        const float bv = db[col];
#pragma unroll
        for (int i = 0; i < 4; ++i) {
#pragma unroll
          for (int rr = 0; rr < 4; ++rr) {
            const int arow = wm + i * 16 + q * 4 + rr;
            const int t = arow >> 4, mm = arow & 15;
            if (t < TSTEPS)
              __builtin_nontemporal_store(
                  acc[i][j2][rr] + bv,
                  &out[(size_t)(mm * TSTEPS + t) * V_ + col]);
          }
        }
      }
      __syncthreads();  // LDS WAR: next tile's STAGE(0,0) vs this tile's reads
    }
  }
}

// ---------- launch ----------
extern "C" void kernel_launch(void* const* d_in, const int* in_sizes, int n_in,
                              void* d_out, int out_size, void* d_ws, size_t ws_size,
                              hipStream_t stream) {
  const float* latent = (const float*)d_in[0];
  const float* trueo  = (const float*)d_in[1];
  const float* gk     = (const float*)d_in[2];
  const float* grk    = (const float*)d_in[3];
  const float* gbias  = (const float*)d_in[4];
  const float* dw     = (const float*)d_in[5];
  const float* db     = (const float*)d_in[6];
  float* out = (float*)d_out;
  char* ws = (char*)d_ws;
  short*    WrecT  = (short*)(ws + 0);          //  6,291,456  [3072][1024] bf16
  short*    GkT    = (short*)(ws + 6291456);    //  3,145,728  [3072][512]  bf16
  short*    DwT    = (short*)(ws + 9437184);    // 65,536,000  [32000][1024] bf16
  short*    teachA = (short*)(ws + 74973184);   //  4,194,304  [4096][512]  bf16 rows t*16+b
  float*    xproj  = (float*)(ws + 79167488);   // 50,331,648  [4096][3072] f32 rows t*16+m
  short*    hist   = (short*)(ws + 129499136);  //  8,421,376  [4112][1024] bf16 h-history
  unsigned* syncb  = (unsigned*)(ws + 137920512); //    8,192  scanflags + frontier

  hipMemsetAsync(syncb, 0, 8192, stream);
  transpose_cvt<<<dim3(96, 32), dim3(32, 8), 0, stream>>>(grk, WrecT, 1024, 3072);
  transpose_cvt<<<dim3(96, 16), dim3(32, 8), 0, stream>>>(gk, GkT, 512, 3072);
  transpose_cvt<<<dim3(1000, 32), dim3(32, 8), 0, stream>>>(dw, DwT, 1024, 32000);
  pack_teacher<<<1024, 256, 0, stream>>>(trueo, teachA);
  gemm_bf16<<<dim3(24, 32), 256, 0, stream>>>(teachA, GkT, gbias, xproj, G_, E_);
  init_h<<<64, 256, 0, stream>>>(latent, hist);
  fused_scan_gemm<<<NBLK_TOT, 256, 0, stream>>>(WrecT, xproj, gbias + G_, latent,
                                                hist, DwT, db, out, syncb);
}